// Round 1
// baseline (299.870 us; speedup 1.0000x reference)
//
#include <hip/hip_runtime.h>
#include <hip/hip_bf16.h>

// NonLocalBlock1D — algebraically collapsed:
//   S[b]  = g_pool[b] @ phi_pool[b]^T          (128x128 per batch)
//   M[b]  = w_w @ S[b] / N                     (256x128)
//   W2[b] = M[b] @ theta_w                     (256x256)
//   b2[b] = M[b] @ theta_b + w_b               (256)
//   wy[b] = W2[b] @ x[b] + b2[b]               (256x8192)
//   out   = BN(wy) + x
// theta is never materialized; the (B,T,N) attention map is never formed.

constexpr int B = 4, C = 256, CI = 128, T = 8192, N = 4096;
constexpr int TT = 128;  // t-tile for conv kernels
constexpr int OT = 64;   // output-row tile
constexpr int KC = 32;   // k-chunk

// ws layout (floats)
constexpr size_t OFF_PHI = 0;                         // B*CI*N
constexpr size_t OFF_G   = OFF_PHI + (size_t)B*CI*N;  // B*CI*N
constexpr size_t OFF_S   = OFF_G   + (size_t)B*CI*N;  // B*CI*CI
constexpr size_t OFF_M   = OFF_S   + (size_t)B*CI*CI; // B*C*CI
constexpr size_t OFF_W2  = OFF_M   + (size_t)B*C*CI;  // B*C*C
constexpr size_t OFF_B2  = OFF_W2  + (size_t)B*C*C;   // B*C
constexpr size_t OFF_WY  = OFF_B2  + (size_t)B*C;     // B*C*T
constexpr size_t OFF_SUM = OFF_WY  + (size_t)B*C*T;   // C (sum) + C (sumsq)
constexpr size_t OFF_A   = OFF_SUM + 2*(size_t)C;     // C
constexpr size_t OFF_SH  = OFF_A   + (size_t)C;       // C

// K1: pooled phi and g convs. Stacked weight rows: [0,128)=phi, [128,256)=g.
__global__ __launch_bounds__(256) void k1_convpool(
    const float* __restrict__ x, const float* __restrict__ phi_w,
    const float* __restrict__ phi_b, const float* __restrict__ g_w,
    const float* __restrict__ g_b, float* __restrict__ phi_pool,
    float* __restrict__ g_pool)
{
    int t0 = blockIdx.x * TT;
    int ro = blockIdx.y * OT;
    int b  = blockIdx.z;

    __shared__ float ws_w[OT][KC];
    __shared__ float xs[KC][TT];

    int tid = threadIdx.x;
    int tx = tid & 31, ty = tid >> 5;   // tx: t-group, ty: row-group (0..7)
    float acc[8][4];
    #pragma unroll
    for (int j = 0; j < 8; ++j)
        #pragma unroll
        for (int i = 0; i < 4; ++i) acc[j][i] = 0.f;

    const float* xb = x + (size_t)b * C * T;

    for (int c0 = 0; c0 < C; c0 += KC) {
        #pragma unroll
        for (int l = 0; l < 8; ++l) {       // W tile: OT*KC = 2048
            int li = tid + l * 256;
            int r = li >> 5, k = li & 31;
            int row = ro + r;
            ws_w[r][k] = (row < CI) ? phi_w[(size_t)row * C + c0 + k]
                                    : g_w[(size_t)(row - CI) * C + c0 + k];
        }
        #pragma unroll
        for (int l = 0; l < 16; ++l) {      // x tile: KC*TT = 4096
            int li = tid + l * 256;
            int k = li >> 7, t = li & 127;
            xs[k][t] = xb[(size_t)(c0 + k) * T + t0 + t];
        }
        __syncthreads();
        for (int k = 0; k < KC; k += 4) {
            float4 xv0 = *reinterpret_cast<const float4*>(&xs[k + 0][tx * 4]);
            float4 xv1 = *reinterpret_cast<const float4*>(&xs[k + 1][tx * 4]);
            float4 xv2 = *reinterpret_cast<const float4*>(&xs[k + 2][tx * 4]);
            float4 xv3 = *reinterpret_cast<const float4*>(&xs[k + 3][tx * 4]);
            #pragma unroll
            for (int j = 0; j < 8; ++j) {
                float4 wv = *reinterpret_cast<const float4*>(&ws_w[ty * 8 + j][k]);
                acc[j][0] += wv.x * xv0.x; acc[j][0] += wv.y * xv1.x;
                acc[j][0] += wv.z * xv2.x; acc[j][0] += wv.w * xv3.x;
                acc[j][1] += wv.x * xv0.y; acc[j][1] += wv.y * xv1.y;
                acc[j][1] += wv.z * xv2.y; acc[j][1] += wv.w * xv3.y;
                acc[j][2] += wv.x * xv0.z; acc[j][2] += wv.y * xv1.z;
                acc[j][2] += wv.z * xv2.z; acc[j][2] += wv.w * xv3.z;
                acc[j][3] += wv.x * xv0.w; acc[j][3] += wv.y * xv1.w;
                acc[j][3] += wv.z * xv2.w; acc[j][3] += wv.w * xv3.w;
            }
        }
        __syncthreads();
    }
    // maxpool2 along t, +bias, write. cols: t0+tx*4+{0..3} -> n = t0/2+2tx+{0,1}
    int n0 = (t0 >> 1) + tx * 2;
    #pragma unroll
    for (int j = 0; j < 8; ++j) {
        int row = ro + ty * 8 + j;
        float m0 = fmaxf(acc[j][0], acc[j][1]);
        float m1 = fmaxf(acc[j][2], acc[j][3]);
        if (row < CI) {
            float bias = phi_b[row];
            float2 v = {m0 + bias, m1 + bias};
            *reinterpret_cast<float2*>(&phi_pool[((size_t)b * CI + row) * N + n0]) = v;
        } else {
            float bias = g_b[row - CI];
            float2 v = {m0 + bias, m1 + bias};
            *reinterpret_cast<float2*>(&g_pool[((size_t)b * CI + (row - CI)) * N + n0]) = v;
        }
    }
}

// K2: S[b,i,j] = sum_n g_pool[b,i,n] * phi_pool[b,j,n]  (atomic partials over n-chunks)
__global__ __launch_bounds__(256) void k2_S(
    const float* __restrict__ phi_pool, const float* __restrict__ g_pool,
    float* __restrict__ S)
{
    int n0 = blockIdx.x * 128;
    int b  = blockIdx.y;
    __shared__ float gs[CI][33];
    __shared__ float ps[CI][33];
    int tid = threadIdx.x;
    int jg = tid & 15, ig = tid >> 4;
    float acc[8][8] = {};
    const float* gp = g_pool + (size_t)b * CI * N;
    const float* pp = phi_pool + (size_t)b * CI * N;
    for (int ks = 0; ks < 128; ks += 32) {
        #pragma unroll
        for (int l = 0; l < 16; ++l) {   // 128 rows x 32 n
            int li = tid + l * 256;
            int r = li >> 5, k = li & 31;
            gs[r][k] = gp[(size_t)r * N + n0 + ks + k];
            ps[r][k] = pp[(size_t)r * N + n0 + ks + k];
        }
        __syncthreads();
        for (int k = 0; k < 32; ++k) {
            float gv[8], pv[8];
            #pragma unroll
            for (int u = 0; u < 8; ++u) gv[u] = gs[ig + 16 * u][k];
            #pragma unroll
            for (int v = 0; v < 8; ++v) pv[v] = ps[jg + 16 * v][k];
            #pragma unroll
            for (int u = 0; u < 8; ++u)
                #pragma unroll
                for (int v = 0; v < 8; ++v) acc[u][v] += gv[u] * pv[v];
        }
        __syncthreads();
    }
    #pragma unroll
    for (int u = 0; u < 8; ++u) {
        int i = ig + 16 * u;
        #pragma unroll
        for (int v = 0; v < 8; ++v) {
            int j = jg + 16 * v;
            atomicAdd(&S[((size_t)b * CI + i) * CI + j], acc[u][v]);
        }
    }
}

// K3a: M[b] = w_w @ S[b] / N   (one thread per output)
__global__ __launch_bounds__(256) void k3a_M(
    const float* __restrict__ w_w, const float* __restrict__ S,
    float* __restrict__ M)
{
    int idx = blockIdx.x * 256 + threadIdx.x;  // B*C*CI
    int j = idx & (CI - 1);
    int r = (idx >> 7) & (C - 1);
    int b = idx >> 15;
    const float* Sb = S + (size_t)b * CI * CI;
    float a = 0.f;
    for (int k = 0; k < CI; ++k) a += w_w[(size_t)r * CI + k] * Sb[(size_t)k * CI + j];
    M[idx] = a * (1.f / N);
}

// K3b: W2[b] = M[b] @ theta_w ; b2[b] = M[b] @ theta_b + w_b
__global__ __launch_bounds__(256) void k3b_W2(
    const float* __restrict__ M, const float* __restrict__ theta_w,
    const float* __restrict__ theta_b, const float* __restrict__ w_b,
    float* __restrict__ W2, float* __restrict__ b2)
{
    int idx = blockIdx.x * 256 + threadIdx.x;  // B*C*C
    int c = idx & (C - 1);
    int r = (idx >> 8) & (C - 1);
    int b = idx >> 16;
    const float* Mb = M + ((size_t)b * C + r) * CI;
    float a = 0.f;
    for (int k = 0; k < CI; ++k) a += Mb[k] * theta_w[(size_t)k * C + c];
    W2[idx] = a;
    if (c == 0) {
        float bv = 0.f;
        for (int k = 0; k < CI; ++k) bv += Mb[k] * theta_b[k];
        b2[(size_t)b * C + r] = bv + w_b[r];
    }
}

// K4: wy[b] = W2[b] @ x[b] + b2[b]; store wy; accumulate per-channel sum/sumsq
__global__ __launch_bounds__(256) void k4_conv2(
    const float* __restrict__ x, const float* __restrict__ W2,
    const float* __restrict__ b2, float* __restrict__ wy,
    float* __restrict__ gsum, float* __restrict__ gsq)
{
    int t0 = blockIdx.x * TT;
    int ro = blockIdx.y * OT;
    int b  = blockIdx.z;

    __shared__ float ws_w[OT][KC];
    __shared__ float xs[KC][TT];

    int tid = threadIdx.x;
    int tx = tid & 31, ty = tid >> 5;
    float acc[8][4];
    #pragma unroll
    for (int j = 0; j < 8; ++j)
        #pragma unroll
        for (int i = 0; i < 4; ++i) acc[j][i] = 0.f;

    const float* xb  = x + (size_t)b * C * T;
    const float* W2b = W2 + (size_t)b * C * C;

    for (int c0 = 0; c0 < C; c0 += KC) {
        #pragma unroll
        for (int l = 0; l < 8; ++l) {
            int li = tid + l * 256;
            int r = li >> 5, k = li & 31;
            ws_w[r][k] = W2b[(size_t)(ro + r) * C + c0 + k];
        }
        #pragma unroll
        for (int l = 0; l < 16; ++l) {
            int li = tid + l * 256;
            int k = li >> 7, t = li & 127;
            xs[k][t] = xb[(size_t)(c0 + k) * T + t0 + t];
        }
        __syncthreads();
        for (int k = 0; k < KC; k += 4) {
            float4 xv0 = *reinterpret_cast<const float4*>(&xs[k + 0][tx * 4]);
            float4 xv1 = *reinterpret_cast<const float4*>(&xs[k + 1][tx * 4]);
            float4 xv2 = *reinterpret_cast<const float4*>(&xs[k + 2][tx * 4]);
            float4 xv3 = *reinterpret_cast<const float4*>(&xs[k + 3][tx * 4]);
            #pragma unroll
            for (int j = 0; j < 8; ++j) {
                float4 wv = *reinterpret_cast<const float4*>(&ws_w[ty * 8 + j][k]);
                acc[j][0] += wv.x * xv0.x; acc[j][0] += wv.y * xv1.x;
                acc[j][0] += wv.z * xv2.x; acc[j][0] += wv.w * xv3.x;
                acc[j][1] += wv.x * xv0.y; acc[j][1] += wv.y * xv1.y;
                acc[j][1] += wv.z * xv2.y; acc[j][1] += wv.w * xv3.y;
                acc[j][2] += wv.x * xv0.z; acc[j][2] += wv.y * xv1.z;
                acc[j][2] += wv.z * xv2.z; acc[j][2] += wv.w * xv3.z;
                acc[j][3] += wv.x * xv0.w; acc[j][3] += wv.y * xv1.w;
                acc[j][3] += wv.z * xv2.w; acc[j][3] += wv.w * xv3.w;
            }
        }
        __syncthreads();
    }
    #pragma unroll
    for (int j = 0; j < 8; ++j) {
        int row = ro + ty * 8 + j;
        float bias = b2[(size_t)b * C + row];
        float4 v;
        v.x = acc[j][0] + bias; v.y = acc[j][1] + bias;
        v.z = acc[j][2] + bias; v.w = acc[j][3] + bias;
        *reinterpret_cast<float4*>(&wy[((size_t)b * C + row) * T + t0 + tx * 4]) = v;
        float ls = v.x + v.y + v.z + v.w;
        float lq = v.x * v.x + v.y * v.y + v.z * v.z + v.w * v.w;
        #pragma unroll
        for (int m = 16; m >= 1; m >>= 1) {
            ls += __shfl_xor(ls, m, 32);
            lq += __shfl_xor(lq, m, 32);
        }
        if (tx == 0) {
            atomicAdd(&gsum[row], ls);
            atomicAdd(&gsq[row], lq);
        }
    }
}

// K4b: finalize BN scale/shift
__global__ void k4b_stats(const float* __restrict__ gsum, const float* __restrict__ gsq,
                          const float* __restrict__ gamma, const float* __restrict__ beta,
                          float* __restrict__ a, float* __restrict__ sh)
{
    int c = threadIdx.x;
    const float invBT = 1.f / (float)(B * T);
    float mean = gsum[c] * invBT;
    float var  = gsq[c] * invBT - mean * mean;
    float av = gamma[c] * rsqrtf(var + 1e-5f);
    a[c]  = av;
    sh[c] = beta[c] - av * mean;
}

// K5: out = a[c]*wy + sh[c] + x
__global__ __launch_bounds__(256) void k5_bn(
    const float* __restrict__ x, const float* __restrict__ wy,
    const float* __restrict__ a, const float* __restrict__ sh,
    float* __restrict__ out)
{
    size_t total4 = (size_t)B * C * T / 4;
    for (size_t i = (size_t)blockIdx.x * blockDim.x + threadIdx.x; i < total4;
         i += (size_t)gridDim.x * blockDim.x) {
        size_t e = i * 4;
        int c = (int)((e / T) % C);
        float4 w4 = reinterpret_cast<const float4*>(wy)[i];
        float4 x4 = reinterpret_cast<const float4*>(x)[i];
        float av = a[c], sv = sh[c];
        float4 o;
        o.x = av * w4.x + sv + x4.x;
        o.y = av * w4.y + sv + x4.y;
        o.z = av * w4.z + sv + x4.z;
        o.w = av * w4.w + sv + x4.w;
        reinterpret_cast<float4*>(out)[i] = o;
    }
}

extern "C" void kernel_launch(void* const* d_in, const int* in_sizes, int n_in,
                              void* d_out, int out_size, void* d_ws, size_t ws_size,
                              hipStream_t stream)
{
    const float* x       = (const float*)d_in[0];
    const float* theta_w = (const float*)d_in[1];
    const float* theta_b = (const float*)d_in[2];
    const float* phi_w   = (const float*)d_in[3];
    const float* phi_b   = (const float*)d_in[4];
    const float* g_w     = (const float*)d_in[5];
    const float* g_b     = (const float*)d_in[6];
    const float* w_w     = (const float*)d_in[7];
    const float* w_b     = (const float*)d_in[8];
    const float* gamma   = (const float*)d_in[9];
    const float* beta    = (const float*)d_in[10];
    float* out = (float*)d_out;
    float* ws  = (float*)d_ws;

    float* phi_pool = ws + OFF_PHI;
    float* g_pool   = ws + OFF_G;
    float* Sbuf     = ws + OFF_S;
    float* Mbuf     = ws + OFF_M;
    float* W2buf    = ws + OFF_W2;
    float* b2buf    = ws + OFF_B2;
    float* wybuf    = ws + OFF_WY;
    float* gsum     = ws + OFF_SUM;
    float* gsq      = gsum + C;
    float* abuf     = ws + OFF_A;
    float* shbuf    = ws + OFF_SH;

    hipMemsetAsync(Sbuf, 0, (size_t)B * CI * CI * sizeof(float), stream);
    hipMemsetAsync(gsum, 0, 2 * (size_t)C * sizeof(float), stream);

    k1_convpool<<<dim3(T / TT, C / OT, B), 256, 0, stream>>>(
        x, phi_w, phi_b, g_w, g_b, phi_pool, g_pool);
    k2_S<<<dim3(N / 128, B), 256, 0, stream>>>(phi_pool, g_pool, Sbuf);
    k3a_M<<<(B * C * CI) / 256, 256, 0, stream>>>(w_w, Sbuf, Mbuf);
    k3b_W2<<<(B * C * C) / 256, 256, 0, stream>>>(Mbuf, theta_w, theta_b, w_b, W2buf, b2buf);
    k4_conv2<<<dim3(T / TT, C / OT, B), 256, 0, stream>>>(
        x, W2buf, b2buf, wybuf, gsum, gsq);
    k4b_stats<<<1, C, 0, stream>>>(gsum, gsq, gamma, beta, abuf, shbuf);
    k5_bn<<<2048, 256, 0, stream>>>(x, wybuf, abuf, shbuf, out);
}

// Round 3
// 284.222 us; speedup vs baseline: 1.0551x; 1.0551x over previous
//
#include <hip/hip_runtime.h>
#include <hip/hip_bf16.h>

// NonLocalBlock1D, algebraically collapsed + split-bf16 MFMA:
//   S[b]  = g_pool[b] @ phi_pool[b]^T      (128x128)
//   M[b]  = w_w @ S[b] / N                 (256x128)
//   W2[b] = M[b] @ theta_w                 (256x256), b2[b] = M[b]@theta_b + w_b
//   wy[b] = W2[b] @ x[b] + b2[b]  -> BN stats pass + fused BN-apply pass
// fp32 emulated as bf16 hi+lo: a*w ~= ah*wh + ah*wl + al*wh  (err ~2^-16)

constexpr int B = 4, C = 256, CI = 128, T = 8192, NN = 4096;

using s16x8 = __attribute__((ext_vector_type(8))) short;
using f32x4 = __attribute__((ext_vector_type(4))) float;

__device__ __forceinline__ unsigned short f2bf(float f) {
    unsigned int x = __float_as_uint(f);
    unsigned int r = (x + 0x7fffu + ((x >> 16) & 1u)) >> 16;   // RNE
    return (unsigned short)r;
}
__device__ __forceinline__ float bf2f(unsigned short u) {
    return __uint_as_float((unsigned int)u << 16);
}

#define MFMA(a, b, c) __builtin_amdgcn_mfma_f32_16x16x32_bf16((a), (b), (c), 0, 0, 0)

// ---- ws layout (bytes) ----
constexpr size_t SZ_XT = (size_t)B * T * C * 2;        // 16MB each
constexpr size_t O_XTH = 0;
constexpr size_t O_XTL = O_XTH + SZ_XT;
constexpr size_t O_WSH = O_XTL + SZ_XT;                // stacked [phi;g] weights bf16
constexpr size_t O_WSL = O_WSH + (size_t)C * C * 2;
constexpr size_t SZ_P  = (size_t)B * CI * NN * 2;      // 4MB each pool array
constexpr size_t O_PH  = O_WSL + (size_t)C * C * 2;
constexpr size_t O_PL  = O_PH + SZ_P;
constexpr size_t O_GH  = O_PL + SZ_P;
constexpr size_t O_GL  = O_GH + SZ_P;
constexpr size_t O_S   = O_GL + SZ_P;                  // fp32 B*CI*CI
constexpr size_t O_M   = O_S  + (size_t)B * CI * CI * 4;
constexpr size_t O_W2H = O_M  + (size_t)B * C * CI * 4;
constexpr size_t O_W2L = O_W2H + (size_t)B * C * C * 2;
constexpr size_t O_B2  = O_W2L + (size_t)B * C * C * 2;
constexpr size_t O_GS  = O_B2 + (size_t)B * C * 4;
constexpr size_t O_GQ  = O_GS + (size_t)C * 4;
constexpr size_t O_A   = O_GQ + (size_t)C * 4;
constexpr size_t O_SH  = O_A  + (size_t)C * 4;

// K0: x (B,C,T) fp32 -> xT hi/lo bf16 in (B,T,C) layout (c contiguous)
__global__ __launch_bounds__(256) void k0_split(
    const float* __restrict__ x, unsigned short* __restrict__ xth,
    unsigned short* __restrict__ xtl)
{
    __shared__ float xs[64][65];   // [t][c], padded
    int t0 = blockIdx.x * 64, c0 = blockIdx.y * 64, b = blockIdx.z;
    int tid = threadIdx.x;
    const float* xb = x + (size_t)b * C * T;
    #pragma unroll
    for (int p = 0; p < 4; ++p) {
        int idx = tid + p * 256;
        int cr = idx >> 4;           // c-local
        int tg = (idx & 15) * 4;     // t-local
        float4 v = *reinterpret_cast<const float4*>(xb + (size_t)(c0 + cr) * T + t0 + tg);
        xs[tg + 0][cr] = v.x; xs[tg + 1][cr] = v.y;
        xs[tg + 2][cr] = v.z; xs[tg + 3][cr] = v.w;
    }
    __syncthreads();
    #pragma unroll
    for (int p = 0; p < 2; ++p) {
        int idx = tid + p * 256;
        int cg = idx & 7, tl = idx >> 3;
        s16x8 hs, ls;
        #pragma unroll
        for (int j = 0; j < 8; ++j) {
            float v = xs[tl][cg * 8 + j];
            unsigned short h = f2bf(v);
            unsigned short l = f2bf(v - bf2f(h));
            hs[j] = (short)h; ls[j] = (short)l;
        }
        size_t dst = ((size_t)b * T + t0 + tl) * C + c0 + cg * 8;
        *reinterpret_cast<s16x8*>(xth + dst) = hs;
        *reinterpret_cast<s16x8*>(xtl + dst) = ls;
    }
}

// K0w: stack [phi_w; g_w] into hi/lo bf16 (256x256, c contiguous)
__global__ __launch_bounds__(256) void k0w(
    const float* __restrict__ phi_w, const float* __restrict__ g_w,
    unsigned short* __restrict__ wsh, unsigned short* __restrict__ wsl)
{
    int idx = blockIdx.x * 256 + threadIdx.x;   // 65536
    int row = idx >> 8, c = idx & 255;
    float v = (row < CI) ? phi_w[(size_t)row * C + c] : g_w[(size_t)(row - CI) * C + c];
    unsigned short h = f2bf(v);
    wsh[idx] = h;
    wsl[idx] = f2bf(v - bf2f(h));
}

// K1: pooled [phi;g] conv via MFMA. Block: 128 t x 256 o, 8 waves.
__global__ __launch_bounds__(512) void k1_mfma(
    const unsigned short* __restrict__ xth, const unsigned short* __restrict__ xtl,
    const unsigned short* __restrict__ wsh, const unsigned short* __restrict__ wsl,
    const float* __restrict__ phi_b, const float* __restrict__ g_b,
    unsigned short* __restrict__ ph, unsigned short* __restrict__ pl,
    unsigned short* __restrict__ gh, unsigned short* __restrict__ gl)
{
    int b = blockIdx.y, t0 = blockIdx.x * 128;
    int tid = threadIdx.x, lane = tid & 63, w = tid >> 6;
    int wo = w & 3, th = w >> 2;
    int lr = lane & 15, lk = lane >> 4;

    f32x4 acc[4][4];   // [osub][tsub]
    #pragma unroll
    for (int i = 0; i < 4; ++i)
        #pragma unroll
        for (int j = 0; j < 4; ++j) acc[i][j] = (f32x4){0.f, 0.f, 0.f, 0.f};

    const unsigned short* ah_b = xth + ((size_t)b * T + t0 + th * 64 + lr) * C + lk * 8;
    const unsigned short* al_b = xtl + ((size_t)b * T + t0 + th * 64 + lr) * C + lk * 8;
    const unsigned short* bh_b = wsh + (size_t)(wo * 64 + lr) * C + lk * 8;
    const unsigned short* bl_b = wsl + (size_t)(wo * 64 + lr) * C + lk * 8;

    for (int c0 = 0; c0 < C; c0 += 32) {
        s16x8 Ah[4], Al[4], Bh[4], Bl[4];
        #pragma unroll
        for (int ts = 0; ts < 4; ++ts) {
            Ah[ts] = *reinterpret_cast<const s16x8*>(ah_b + (size_t)ts * 16 * C + c0);
            Al[ts] = *reinterpret_cast<const s16x8*>(al_b + (size_t)ts * 16 * C + c0);
        }
        #pragma unroll
        for (int os = 0; os < 4; ++os) {
            Bh[os] = *reinterpret_cast<const s16x8*>(bh_b + (size_t)os * 16 * C + c0);
            Bl[os] = *reinterpret_cast<const s16x8*>(bl_b + (size_t)os * 16 * C + c0);
        }
        #pragma unroll
        for (int os = 0; os < 4; ++os)
            #pragma unroll
            for (int ts = 0; ts < 4; ++ts) {
                acc[os][ts] = MFMA(Ah[ts], Bh[os], acc[os][ts]);
                acc[os][ts] = MFMA(Al[ts], Bh[os], acc[os][ts]);
                acc[os][ts] = MFMA(Ah[ts], Bl[os], acc[os][ts]);
            }
    }

    // epilogue: maxpool pairs (t rows are lane-local), +bias, pack hi|lo, LDS transpose
    __shared__ unsigned int pool_s[256][65];
    #pragma unroll
    for (int os = 0; os < 4; ++os) {
        int o = wo * 64 + os * 16 + lr;
        float bias = (o < CI) ? phi_b[o] : g_b[o - CI];
        #pragma unroll
        for (int ts = 0; ts < 4; ++ts) {
            f32x4 v = acc[os][ts];
            float m0 = fmaxf(v[0], v[1]) + bias;
            float m1 = fmaxf(v[2], v[3]) + bias;
            int nl = th * 32 + ts * 8 + lk * 2;
            unsigned short h0 = f2bf(m0), h1 = f2bf(m1);
            unsigned int u0 = (unsigned int)h0 | ((unsigned int)f2bf(m0 - bf2f(h0)) << 16);
            unsigned int u1 = (unsigned int)h1 | ((unsigned int)f2bf(m1 - bf2f(h1)) << 16);
            pool_s[o][nl] = u0;
            pool_s[o][nl + 1] = u1;
        }
    }
    __syncthreads();
    int o = tid >> 1, hf = tid & 1;
    size_t n0 = (size_t)(t0 >> 1) + hf * 32;
    unsigned short* dh = (o < CI ? ph + ((size_t)b * CI + o) * NN
                                 : gh + ((size_t)b * CI + o - CI) * NN) + n0;
    unsigned short* dl = (o < CI ? pl + ((size_t)b * CI + o) * NN
                                 : gl + ((size_t)b * CI + o - CI) * NN) + n0;
    #pragma unroll
    for (int g4 = 0; g4 < 4; ++g4) {
        s16x8 hs, ls;
        #pragma unroll
        for (int j = 0; j < 8; ++j) {
            unsigned int u = pool_s[o][hf * 32 + g4 * 8 + j];
            hs[j] = (short)(u & 0xffffu);
            ls[j] = (short)(u >> 16);
        }
        *reinterpret_cast<s16x8*>(dh + g4 * 8) = hs;
        *reinterpret_cast<s16x8*>(dl + g4 * 8) = ls;
    }
}

// K2: S[b,i,j] = sum_n g[i,n]*phi[j,n], split MFMA, atomic partials over n-chunks.
__global__ __launch_bounds__(256) void k2_mfma(
    const unsigned short* __restrict__ ph, const unsigned short* __restrict__ pl,
    const unsigned short* __restrict__ gh, const unsigned short* __restrict__ gl,
    float* __restrict__ S)
{
    int b = blockIdx.y, n0 = blockIdx.x * 512;
    int tid = threadIdx.x, lane = tid & 63, w = tid >> 6;
    int lr = lane & 15, lk = lane >> 4;

    f32x4 acc[2][8];   // [isub][jsub]
    #pragma unroll
    for (int i = 0; i < 2; ++i)
        #pragma unroll
        for (int j = 0; j < 8; ++j) acc[i][j] = (f32x4){0.f, 0.f, 0.f, 0.f};

    const unsigned short* ah_b = gh + ((size_t)b * CI + w * 32 + lr) * NN + n0 + lk * 8;
    const unsigned short* al_b = gl + ((size_t)b * CI + w * 32 + lr) * NN + n0 + lk * 8;
    const unsigned short* bh_b = ph + ((size_t)b * CI + lr) * NN + n0 + lk * 8;
    const unsigned short* bl_b = pl + ((size_t)b * CI + lr) * NN + n0 + lk * 8;

    for (int ks = 0; ks < 16; ++ks) {
        s16x8 Ah[2], Al[2], Bh[8], Bl[8];
        #pragma unroll
        for (int is = 0; is < 2; ++is) {
            Ah[is] = *reinterpret_cast<const s16x8*>(ah_b + (size_t)is * 16 * NN + ks * 32);
            Al[is] = *reinterpret_cast<const s16x8*>(al_b + (size_t)is * 16 * NN + ks * 32);
        }
        #pragma unroll
        for (int js = 0; js < 8; ++js) {
            Bh[js] = *reinterpret_cast<const s16x8*>(bh_b + (size_t)js * 16 * NN + ks * 32);
            Bl[js] = *reinterpret_cast<const s16x8*>(bl_b + (size_t)js * 16 * NN + ks * 32);
        }
        #pragma unroll
        for (int is = 0; is < 2; ++is)
            #pragma unroll
            for (int js = 0; js < 8; ++js) {
                acc[is][js] = MFMA(Ah[is], Bh[js], acc[is][js]);
                acc[is][js] = MFMA(Al[is], Bh[js], acc[is][js]);
                acc[is][js] = MFMA(Ah[is], Bl[js], acc[is][js]);
            }
    }
    #pragma unroll
    for (int is = 0; is < 2; ++is) {
        int i0 = w * 32 + is * 16 + lk * 4;
        #pragma unroll
        for (int js = 0; js < 8; ++js) {
            int j = js * 16 + lr;
            #pragma unroll
            for (int r = 0; r < 4; ++r)
                atomicAdd(&S[((size_t)b * CI + i0 + r) * CI + j], acc[is][js][r]);
        }
    }
}

// K3a: M[b] = w_w @ S[b] / N
__global__ __launch_bounds__(256) void k3a_M(
    const float* __restrict__ w_w, const float* __restrict__ S, float* __restrict__ M)
{
    int idx = blockIdx.x * 256 + threadIdx.x;  // B*C*CI
    int j = idx & (CI - 1);
    int r = (idx >> 7) & (C - 1);
    int b = idx >> 15;
    const float* Sb = S + (size_t)b * CI * CI;
    float a = 0.f;
    for (int k = 0; k < CI; ++k) a += w_w[(size_t)r * CI + k] * Sb[(size_t)k * CI + j];
    M[idx] = a * (1.f / NN);
}

// K3b: W2[b] = M[b] @ theta_w (-> bf16 hi/lo); b2[b] = M[b] @ theta_b + w_b
__global__ __launch_bounds__(256) void k3b_W2(
    const float* __restrict__ M, const float* __restrict__ theta_w,
    const float* __restrict__ theta_b, const float* __restrict__ w_b,
    unsigned short* __restrict__ w2h, unsigned short* __restrict__ w2l,
    float* __restrict__ b2)
{
    int idx = blockIdx.x * 256 + threadIdx.x;  // B*C*C
    int c = idx & (C - 1);
    int r = (idx >> 8) & (C - 1);
    int b = idx >> 16;
    const float* Mb = M + ((size_t)b * C + r) * CI;
    float a = 0.f;
    for (int k = 0; k < CI; ++k) a += Mb[k] * theta_w[(size_t)k * C + c];
    unsigned short h = f2bf(a);
    w2h[idx] = h;
    w2l[idx] = f2bf(a - bf2f(h));
    if (c == 0) {
        float bv = 0.f;
        for (int k = 0; k < CI; ++k) bv += Mb[k] * theta_b[k];
        b2[(size_t)b * C + r] = bv + w_b[r];
    }
}

// K45: wy = W2[b]@x + b2.  MODE 0: BN stats (atomics).  MODE 1: out = a*wy+sh+x.
template <int MODE>
__global__ __launch_bounds__(512) void k45_mfma(
    const unsigned short* __restrict__ xth, const unsigned short* __restrict__ xtl,
    const unsigned short* __restrict__ w2h, const unsigned short* __restrict__ w2l,
    const float* __restrict__ b2, const float* __restrict__ x,
    const float* __restrict__ abuf, const float* __restrict__ shbuf,
    float* __restrict__ gsum, float* __restrict__ gsq, float* __restrict__ out)
{
    int b = blockIdx.y, t0 = blockIdx.x * 128;
    int tid = threadIdx.x, lane = tid & 63, w = tid >> 6;
    int wo = w & 3, th = w >> 2;
    int lr = lane & 15, lk = lane >> 4;

    f32x4 acc[4][4];
    #pragma unroll
    for (int i = 0; i < 4; ++i)
        #pragma unroll
        for (int j = 0; j < 4; ++j) acc[i][j] = (f32x4){0.f, 0.f, 0.f, 0.f};

    const unsigned short* ah_b = xth + ((size_t)b * T + t0 + th * 64 + lr) * C + lk * 8;
    const unsigned short* al_b = xtl + ((size_t)b * T + t0 + th * 64 + lr) * C + lk * 8;
    const unsigned short* bh_b = w2h + (size_t)b * C * C + (size_t)(wo * 64 + lr) * C + lk * 8;
    const unsigned short* bl_b = w2l + (size_t)b * C * C + (size_t)(wo * 64 + lr) * C + lk * 8;

    for (int c0 = 0; c0 < C; c0 += 32) {
        s16x8 Ah[4], Al[4], Bh[4], Bl[4];
        #pragma unroll
        for (int ts = 0; ts < 4; ++ts) {
            Ah[ts] = *reinterpret_cast<const s16x8*>(ah_b + (size_t)ts * 16 * C + c0);
            Al[ts] = *reinterpret_cast<const s16x8*>(al_b + (size_t)ts * 16 * C + c0);
        }
        #pragma unroll
        for (int os = 0; os < 4; ++os) {
            Bh[os] = *reinterpret_cast<const s16x8*>(bh_b + (size_t)os * 16 * C + c0);
            Bl[os] = *reinterpret_cast<const s16x8*>(bl_b + (size_t)os * 16 * C + c0);
        }
        #pragma unroll
        for (int os = 0; os < 4; ++os)
            #pragma unroll
            for (int ts = 0; ts < 4; ++ts) {
                acc[os][ts] = MFMA(Ah[ts], Bh[os], acc[os][ts]);
                acc[os][ts] = MFMA(Al[ts], Bh[os], acc[os][ts]);
                acc[os][ts] = MFMA(Ah[ts], Bl[os], acc[os][ts]);
            }
    }

    #pragma unroll
    for (int os = 0; os < 4; ++os) {
        int o = wo * 64 + os * 16 + lr;
        float bv = b2[(size_t)b * C + o];
        if (MODE == 0) {
            float s = 0.f, q = 0.f;
            #pragma unroll
            for (int ts = 0; ts < 4; ++ts)
                #pragma unroll
                for (int r = 0; r < 4; ++r) {
                    float v = acc[os][ts][r] + bv;
                    s += v; q += v * v;
                }
            s += __shfl_xor(s, 16); s += __shfl_xor(s, 32);
            q += __shfl_xor(q, 16); q += __shfl_xor(q, 32);
            if (lk == 0) { atomicAdd(&gsum[o], s); atomicAdd(&gsq[o], q); }
        } else {
            float av = abuf[o], sv = shbuf[o];
            #pragma unroll
            for (int ts = 0; ts < 4; ++ts) {
                int t = t0 + th * 64 + ts * 16 + lk * 4;
                size_t base = ((size_t)b * C + o) * T + t;
                float4 xv = *reinterpret_cast<const float4*>(x + base);
                float4 ov;
                ov.x = av * (acc[os][ts][0] + bv) + sv + xv.x;
                ov.y = av * (acc[os][ts][1] + bv) + sv + xv.y;
                ov.z = av * (acc[os][ts][2] + bv) + sv + xv.z;
                ov.w = av * (acc[os][ts][3] + bv) + sv + xv.w;
                *reinterpret_cast<float4*>(out + base) = ov;
            }
        }
    }
}

// K4b: finalize BN scale/shift
__global__ void k4b_stats(const float* __restrict__ gsum, const float* __restrict__ gsq,
                          const float* __restrict__ gamma, const float* __restrict__ beta,
                          float* __restrict__ a, float* __restrict__ sh)
{
    int c = threadIdx.x;
    const float invBT = 1.f / (float)(B * T);
    float mean = gsum[c] * invBT;
    float var  = gsq[c] * invBT - mean * mean;
    float av = gamma[c] * rsqrtf(var + 1e-5f);
    a[c]  = av;
    sh[c] = beta[c] - av * mean;
}

extern "C" void kernel_launch(void* const* d_in, const int* in_sizes, int n_in,
                              void* d_out, int out_size, void* d_ws, size_t ws_size,
                              hipStream_t stream)
{
    const float* x       = (const float*)d_in[0];
    const float* theta_w = (const float*)d_in[1];
    const float* theta_b = (const float*)d_in[2];
    const float* phi_w   = (const float*)d_in[3];
    const float* phi_b   = (const float*)d_in[4];
    const float* g_w     = (const float*)d_in[5];
    const float* g_b     = (const float*)d_in[6];
    const float* w_w     = (const float*)d_in[7];
    const float* w_b     = (const float*)d_in[8];
    const float* gamma   = (const float*)d_in[9];
    const float* beta    = (const float*)d_in[10];
    float* out = (float*)d_out;
    char* ws = (char*)d_ws;

    unsigned short* xth = (unsigned short*)(ws + O_XTH);
    unsigned short* xtl = (unsigned short*)(ws + O_XTL);
    unsigned short* wsh = (unsigned short*)(ws + O_WSH);
    unsigned short* wsl = (unsigned short*)(ws + O_WSL);
    unsigned short* ph  = (unsigned short*)(ws + O_PH);
    unsigned short* pl  = (unsigned short*)(ws + O_PL);
    unsigned short* gh  = (unsigned short*)(ws + O_GH);
    unsigned short* gl  = (unsigned short*)(ws + O_GL);
    float* Sbuf  = (float*)(ws + O_S);
    float* Mbuf  = (float*)(ws + O_M);
    unsigned short* w2h = (unsigned short*)(ws + O_W2H);
    unsigned short* w2l = (unsigned short*)(ws + O_W2L);
    float* b2    = (float*)(ws + O_B2);
    float* gsum  = (float*)(ws + O_GS);
    float* gsq   = (float*)(ws + O_GQ);
    float* abuf  = (float*)(ws + O_A);
    float* shbuf = (float*)(ws + O_SH);

    hipMemsetAsync(Sbuf, 0, (size_t)B * CI * CI * sizeof(float), stream);
    hipMemsetAsync(gsum, 0, 2 * (size_t)C * sizeof(float), stream);

    k0_split<<<dim3(T / 64, C / 64, B), 256, 0, stream>>>(x, xth, xtl);
    k0w<<<dim3(C * C / 256), 256, 0, stream>>>(phi_w, g_w, wsh, wsl);
    k1_mfma<<<dim3(T / 128, B), 512, 0, stream>>>(xth, xtl, wsh, wsl, phi_b, g_b,
                                                  ph, pl, gh, gl);
    k2_mfma<<<dim3(NN / 512, B), 256, 0, stream>>>(ph, pl, gh, gl, Sbuf);
    k3a_M<<<dim3(B * C * CI / 256), 256, 0, stream>>>(w_w, Sbuf, Mbuf);
    k3b_W2<<<dim3(B * C * C / 256), 256, 0, stream>>>(Mbuf, theta_w, theta_b, w_b,
                                                      w2h, w2l, b2);
    k45_mfma<0><<<dim3(T / 128, B), 512, 0, stream>>>(xth, xtl, w2h, w2l, b2, x,
                                                      abuf, shbuf, gsum, gsq, out);
    k4b_stats<<<1, C, 0, stream>>>(gsum, gsq, gamma, beta, abuf, shbuf);
    k45_mfma<1><<<dim3(T / 128, B), 512, 0, stream>>>(xth, xtl, w2h, w2l, b2, x,
                                                      abuf, shbuf, gsum, gsq, out);
}